// Round 1
// baseline (373.233 us; speedup 1.0000x reference)
//
#include <hip/hip_runtime.h>

#define PI_F 3.14159265358979323846f

// ---------------- workspace layout (float offsets) ----------------
#define WS_SPEC   0u          // 32*128*1024  [b][t][k]
#define WS_H0     4194304u    // 32*32*128    [b][o][t]
#define WS_ACC    4325376u    // 32*128*32    [b][t][o]
#define WS_V      4456448u    // 32*32*128    [b][c][t]
#define WS_WTIN   4587520u    // 1024*32      [k][o]
#define WS_WST    4620288u    // 32*256       [m][o2]
#define WS_WDT    4628480u    // 256*32       [o2][c]
#define WS_FRAMES 4636672u    // 32*32*2048   [c][f][j]
#define WS_RES    6733824u    // 32*32768     [c][s]
// total 7782400 floats = ~29.7 MB

// ---- 2048-pt complex DIT FFT, input already in bit-reversed order, 256 thr ----
__device__ __forceinline__ void fft2048_stages(float2* buf, int tid) {
  for (int stage = 0; stage < 11; ++stage) {
    int half = 1 << stage;
    float base = -PI_F / (float)half;   // -2*pi/len
    for (int t = tid; t < 1024; t += 256) {
      int j  = t & (half - 1);
      int i0 = ((t >> stage) << (stage + 1)) + j;
      int i1 = i0 + half;
      float s, c;
      __sincosf(base * (float)j, &s, &c);   // e^{-i*2pi*j/len} = c + i*s
      float2 u = buf[i0];
      float2 w = buf[i1];
      float tr = c * w.x - s * w.y;
      float ti = c * w.y + s * w.x;
      buf[i0] = make_float2(u.x + tr, u.y + ti);
      buf[i1] = make_float2(u.x - tr, u.y - ti);
    }
    __syncthreads();
  }
}

// ---------------- STFT: |rfft(frame*hann)|/sqrt(2048), keep k<1024 ----------------
__global__ __launch_bounds__(256) void k_stft(const float* __restrict__ audio,
                                              float* __restrict__ spec) {
  __shared__ float2 buf[2048];
  int b = blockIdx.x >> 7;
  int f = blockIdx.x & 127;
  for (int j = threadIdx.x; j < 2048; j += 256) {
    int idx = f * 256 + j;
    float v = (idx < 32768) ? audio[b * 32768 + idx] : 0.f;
    float h = 0.5f - 0.5f * __cosf(0.0030679615757712823f * (float)j); // 2pi/2048
    buf[__brev((unsigned)j) >> 21] = make_float2(v * h, 0.f);
  }
  __syncthreads();
  fft2048_stages(buf, threadIdx.x);
  const float scale = 0.022097086912079608f;  // 1/sqrt(2048)
  for (int k = threadIdx.x; k < 1024; k += 256) {
    float2 X = buf[k];
    spec[(b * 128 + f) * 1024 + k] = sqrtf(X.x * X.x + X.y * X.y) * scale;
  }
}

// ---------------- weight transposes ----------------
__global__ __launch_bounds__(256) void k_prep(const float* __restrict__ Win,
                                              const float* __restrict__ Ws,
                                              const float* __restrict__ Wd,
                                              float* __restrict__ WT,
                                              float* __restrict__ WsT,
                                              float* __restrict__ WdT) {
  int i = blockIdx.x * 256 + threadIdx.x;
  if (i < 32768) { int o = i >> 10, k = i & 1023; WT[k * 32 + o] = Win[i]; }
  if (i < 8192)  { int o2 = i >> 5, m = i & 31;   WsT[m * 256 + o2] = Ws[i]; }
  if (i < 8192)  { int c = i >> 8, o2 = i & 255;  WdT[o2 * 32 + c] = Wd[i]; }
}

// ---------------- proj_in: h0[b,o,t] = sum_k WT[k][o]*spec[b,t,k] + bias ----------------
__global__ __launch_bounds__(256) void k_proj_in(const float* __restrict__ spec,
                                                 const float* __restrict__ WT,
                                                 const float* __restrict__ bias,
                                                 float* __restrict__ h0) {
  __shared__ float specL[8][1024];
  __shared__ float red[32][8][8];   // [o][tt][p]
  int b  = blockIdx.x >> 4;
  int t0 = (blockIdx.x & 15) * 8;
  for (int i = threadIdx.x; i < 8192; i += 256) {
    int tt = i >> 10, k = i & 1023;
    specL[tt][k] = spec[(b * 128 + t0 + tt) * 1024 + k];
  }
  __syncthreads();
  int o = threadIdx.x & 31, p = threadIdx.x >> 5;
  float part[8] = {0.f,0.f,0.f,0.f,0.f,0.f,0.f,0.f};
  for (int i = 0; i < 128; ++i) {
    int k = p * 128 + ((i + p * 4) & 127);   // stagger: conflict-free banks across p
    float w = WT[k * 32 + o];
#pragma unroll
    for (int tt = 0; tt < 8; ++tt) part[tt] += w * specL[tt][k];
  }
#pragma unroll
  for (int tt = 0; tt < 8; ++tt) red[o][tt][p] = part[tt];
  __syncthreads();
  int oo = threadIdx.x >> 3, tt2 = threadIdx.x & 7;
  float s = bias[oo];
#pragma unroll
  for (int p2 = 0; p2 < 8; ++p2) s += red[oo][tt2][p2];
  h0[b * 4096 + oo * 128 + t0 + tt2] = s;
}

// ---------------- 8-block anticausal chain, one WG per batch ----------------
__global__ __launch_bounds__(1024) void k_chain(const float* __restrict__ h0,
                                                const float* __restrict__ bw,
                                                const float* __restrict__ bb,
                                                float* __restrict__ accout) {
  __shared__ float hL[32][128];
  __shared__ float w0L[32][32], w1L[32][32];
  __shared__ float bL[32];
  __shared__ float red[16];
  __shared__ float normL;
  int b = blockIdx.x;
  int tid = threadIdx.x;
  int t = tid & 127, og = tid >> 7;   // og 0..7
  for (int i = tid; i < 4096; i += 1024) hL[i >> 7][i & 127] = h0[b * 4096 + i];
  float acc[4] = {0.f, 0.f, 0.f, 0.f};
  const int DIL[8] = {1, 2, 4, 8, 16, 32, 64, 1};
  for (int blk = 0; blk < 8; ++blk) {
    __syncthreads();
    {
      int o = tid >> 5, m = tid & 31;   // tid < 1024 covers all 32x32
      w0L[o][m] = bw[((blk * 32 + o) * 32 + m) * 2 + 0];
      w1L[o][m] = bw[((blk * 32 + o) * 32 + m) * 2 + 1];
      if (tid < 32) bL[tid] = bb[blk * 32 + tid];
    }
    __syncthreads();
    int d = DIL[blk];
    int t2 = t + d;
    int t2c = (t2 < 128) ? t2 : 0;
    float fm = (t2 < 128) ? 1.f : 0.f;
    float y[4];
#pragma unroll
    for (int n = 0; n < 4; ++n) y[n] = bL[og * 4 + n];
    for (int m = 0; m < 32; ++m) {
      float hv = hL[m][t];
      float hf = hL[m][t2c] * fm;
#pragma unroll
      for (int n = 0; n < 4; ++n)
        y[n] += w0L[og * 4 + n][m] * hv + w1L[og * 4 + n][m] * hf;
    }
    float lmax = 0.f;
#pragma unroll
    for (int n = 0; n < 4; ++n) {
      float s = y[n];
      s = (s > 0.f) ? s : 0.2f * s;     // leaky_relu 0.2
      s += hL[og * 4 + n][t];           // residual
      y[n] = s;
      lmax = fmaxf(lmax, fabsf(s));
    }
    for (int off = 32; off > 0; off >>= 1)
      lmax = fmaxf(lmax, __shfl_down(lmax, off, 64));
    if ((tid & 63) == 0) red[tid >> 6] = lmax;
    __syncthreads();
    if (tid == 0) {
      float m = 0.f;
      for (int i2 = 0; i2 < 16; ++i2) m = fmaxf(m, red[i2]);
      normL = 1.f / (m + 1e-8f);
    }
    __syncthreads();
    float nm = normL;
#pragma unroll
    for (int n = 0; n < 4; ++n) {
      float hv = y[n] * nm;
      hL[og * 4 + n][t] = hv;
      acc[n] += hv;
    }
  }
#pragma unroll
  for (int n = 0; n < 4; ++n)
    accout[b * 4096 + t * 32 + og * 4 + n] = acc[n];
}

// ---------------- sparse (relu proj 32->256, to d_out) + dense (256->32, to ws) ----------------
__global__ __launch_bounds__(256) void k_sparse_dense(const float* __restrict__ acc,
                                                      const float* __restrict__ WsT,
                                                      const float* __restrict__ bs,
                                                      const float* __restrict__ WdT,
                                                      const float* __restrict__ bd,
                                                      float* __restrict__ out_sparse,
                                                      float* __restrict__ v) {
  __shared__ float accL[32];
  __shared__ float sL[256];
  __shared__ float red[8][32];
  int b = blockIdx.x >> 7, t = blockIdx.x & 127;
  int tid = threadIdx.x;
  if (tid < 32) accL[tid] = acc[b * 4096 + t * 32 + tid];
  __syncthreads();
  float s = bs[tid];
  for (int m = 0; m < 32; ++m) s += WsT[m * 256 + tid] * accL[m];
  s = fmaxf(s, 0.f);
  out_sparse[b * 32768 + tid * 128 + t] = s;
  sL[tid] = s;
  __syncthreads();
  int c = tid & 31, p = tid >> 5;
  float part = 0.f;
  for (int j = 0; j < 32; ++j) {
    int o2 = p * 32 + j;
    part += WdT[o2 * 32 + c] * sL[o2];
  }
  red[p][c] = part;
  __syncthreads();
  if (tid < 32) {
    float vv = bd[tid];
    for (int p2 = 0; p2 < 8; ++p2) vv += red[p2][tid];
    v[b * 4096 + tid * 128 + t] = vv;
  }
}

// ---------------- resonance frames: irfft_2048(c^(f+1)) * hann, f<32 only ----------------
__global__ __launch_bounds__(256) void k_res_frames(const float* __restrict__ resin,
                                                    float* __restrict__ frames) {
  __shared__ float2 buf[2048];
  int c = blockIdx.x >> 5;
  int f = blockIdx.x & 31;
  float e = (float)(f + 1);
  for (int k = threadIdx.x; k < 2048; k += 256) {
    int kk = (k <= 1024) ? k : 2048 - k;   // Hermitian (real) extension
    float cv = resin[c * 1025 + kk];
    cv = fminf(fmaxf(cv, 0.f), 0.9999f);
    float m = __powf(cv, e);
    buf[__brev((unsigned)k) >> 21] = make_float2(m, 0.f);
  }
  __syncthreads();
  fft2048_stages(buf, threadIdx.x);
  for (int j = threadIdx.x; j < 2048; j += 256) {
    float h = 0.5f - 0.5f * __cosf(0.0030679615757712823f * (float)j);
    frames[(c * 32 + f) * 2048 + j] = buf[j].x * (1.f / 2048.f) * h;
  }
}

// ---------------- overlap-add (hop 1024): at most 2 frames per sample ----------------
__global__ __launch_bounds__(256) void k_res_assemble(const float* __restrict__ frames,
                                                      float* __restrict__ res) {
  int i = blockIdx.x * 256 + threadIdx.x;   // 0 .. 32*32768
  int c = i >> 15, s = i & 32767;
  int g = s >> 10, j0 = s & 1023;
  float v = frames[(c * 32 + g) * 2048 + j0];
  if (g > 0) v += frames[(c * 32 + g - 1) * 2048 + j0 + 1024];
  res[i] = v;
}

// ---------------- final conv: y[b,256q+r] += sum_c sum_u v[b,c,q-u]*res[c,256u+r] ----------------
__global__ __launch_bounds__(256) void k_conv(const float* __restrict__ v,
                                              const float* __restrict__ res,
                                              float* __restrict__ y) {
  __shared__ float vL[4096];
  int b     = blockIdx.x >> 5;
  int qt    = (blockIdx.x >> 2) & 7;
  int chunk = blockIdx.x & 3;
  int q0 = qt * 16;
  int ulim = q0 + 16;
  int u0 = chunk * 32;
  if (u0 >= ulim) return;                      // empty chunk (uniform per block)
  int uend = (u0 + 32 < ulim) ? u0 + 32 : ulim;
  int r = threadIdx.x;
  for (int i = threadIdx.x; i < 4096; i += 256) vL[i] = v[b * 4096 + i];
  __syncthreads();
  float acc[16];
#pragma unroll
  for (int qi = 0; qi < 16; ++qi) acc[qi] = 0.f;
  for (int c = 0; c < 32; ++c) {
    const float* vrow = &vL[c * 128];
    const float* rrow = &res[c * 32768 + r];
    float vw[16];                               // vw[j] == v[c][q0+j-u] at loop entry
#pragma unroll
    for (int j = 0; j < 16; ++j) vw[j] = vrow[q0 - u0 + j];   // u0 <= q0 always
#pragma unroll 4
    for (int u = u0; u < uend; ++u) {
      float rv = rrow[u * 256];
#pragma unroll
      for (int qi = 0; qi < 16; ++qi) acc[qi] += vw[qi] * rv;
#pragma unroll
      for (int j = 15; j > 0; --j) vw[j] = vw[j - 1];
      int ni = q0 - u - 1;
      vw[0] = (ni >= 0) ? vrow[ni] : 0.f;       // masks u > q terms with zeros
    }
  }
#pragma unroll
  for (int qi = 0; qi < 16; ++qi)
    atomicAdd(&y[b * 32768 + (q0 + qi) * 256 + r], acc[qi]);
}

extern "C" void kernel_launch(void* const* d_in, const int* in_sizes, int n_in,
                              void* d_out, int out_size, void* d_ws, size_t ws_size,
                              hipStream_t stream) {
  const float* audio = (const float*)d_in[0];
  const float* Win   = (const float*)d_in[1];
  const float* bin   = (const float*)d_in[2];
  const float* bw    = (const float*)d_in[3];
  const float* bb    = (const float*)d_in[4];
  const float* Ws    = (const float*)d_in[5];
  const float* bs    = (const float*)d_in[6];
  const float* Wd    = (const float*)d_in[7];
  const float* bd    = (const float*)d_in[8];
  const float* reson = (const float*)d_in[9];

  float* out = (float*)d_out;           // [0,1048576) = y ; [1048576,2097152) = sparse
  float* ws  = (float*)d_ws;

  float* spec   = ws + WS_SPEC;
  float* h0     = ws + WS_H0;
  float* accb   = ws + WS_ACC;
  float* vbuf   = ws + WS_V;
  float* WT     = ws + WS_WTIN;
  float* WsT    = ws + WS_WST;
  float* WdT    = ws + WS_WDT;
  float* frames = ws + WS_FRAMES;
  float* resbuf = ws + WS_RES;

  // zero y region (atomicAdd target); d_out is poisoned before every launch
  hipMemsetAsync(d_out, 0, 1048576u * sizeof(float), stream);

  k_prep<<<128, 256, 0, stream>>>(Win, Ws, Wd, WT, WsT, WdT);
  k_res_frames<<<1024, 256, 0, stream>>>(reson, frames);
  k_res_assemble<<<4096, 256, 0, stream>>>(frames, resbuf);
  k_stft<<<4096, 256, 0, stream>>>(audio, spec);
  k_proj_in<<<512, 256, 0, stream>>>(spec, WT, bin, h0);
  k_chain<<<32, 1024, 0, stream>>>(h0, bw, bb, accb);
  k_sparse_dense<<<4096, 256, 0, stream>>>(accb, WsT, bs, WdT, bd, out + 1048576, vbuf);
  k_conv<<<1024, 256, 0, stream>>>(vbuf, resbuf, out);
}

// Round 2
// 327.497 us; speedup vs baseline: 1.1397x; 1.1397x over previous
//
#include <hip/hip_runtime.h>

#define PI_F 3.14159265358979323846f

// ---------------- workspace layout (float offsets) ----------------
#define WS_SPEC   0u          // 32*128*1024  [b][t][k]
#define WS_H0     4194304u    // 32*32*128    [b][o][t]
#define WS_ACC    4325376u    // 32*128*32    [b][t][o]
#define WS_V      4456448u    // 32*32*128    [b][c][t]
#define WS_WTIN   4587520u    // 1024*32      [k][o]
#define WS_WST    4620288u    // 32*256       [m][o2]
#define WS_WDT    4628480u    // 256*32       [o2][c]
#define WS_FRAMES 4636672u    // 32*32*2048   [c][f][j]
#define WS_RES    6733824u    // 32*32768     [c][s]
// total 7782400 floats = ~29.7 MB

// ---- 2048-pt complex DIT FFT, input already in bit-reversed order, 256 thr ----
__device__ __forceinline__ void fft2048_stages(float2* buf, int tid) {
  for (int stage = 0; stage < 11; ++stage) {
    int half = 1 << stage;
    float base = -PI_F / (float)half;   // -2*pi/len
    for (int t = tid; t < 1024; t += 256) {
      int j  = t & (half - 1);
      int i0 = ((t >> stage) << (stage + 1)) + j;
      int i1 = i0 + half;
      float s, c;
      __sincosf(base * (float)j, &s, &c);   // e^{-i*2pi*j/len} = c + i*s
      float2 u = buf[i0];
      float2 w = buf[i1];
      float tr = c * w.x - s * w.y;
      float ti = c * w.y + s * w.x;
      buf[i0] = make_float2(u.x + tr, u.y + ti);
      buf[i1] = make_float2(u.x - tr, u.y - ti);
    }
    __syncthreads();
  }
}

// ---------------- STFT: |rfft(frame*hann)|/sqrt(2048), keep k<1024 ----------------
__global__ __launch_bounds__(256) void k_stft(const float* __restrict__ audio,
                                              float* __restrict__ spec) {
  __shared__ float2 buf[2048];
  int b = blockIdx.x >> 7;
  int f = blockIdx.x & 127;
  for (int j = threadIdx.x; j < 2048; j += 256) {
    int idx = f * 256 + j;
    float v = (idx < 32768) ? audio[b * 32768 + idx] : 0.f;
    float h = 0.5f - 0.5f * __cosf(0.0030679615757712823f * (float)j); // 2pi/2048
    buf[__brev((unsigned)j) >> 21] = make_float2(v * h, 0.f);
  }
  __syncthreads();
  fft2048_stages(buf, threadIdx.x);
  const float scale = 0.022097086912079608f;  // 1/sqrt(2048)
  for (int k = threadIdx.x; k < 1024; k += 256) {
    float2 X = buf[k];
    spec[(b * 128 + f) * 1024 + k] = sqrtf(X.x * X.x + X.y * X.y) * scale;
  }
}

// ---------------- weight transposes ----------------
__global__ __launch_bounds__(256) void k_prep(const float* __restrict__ Win,
                                              const float* __restrict__ Ws,
                                              const float* __restrict__ Wd,
                                              float* __restrict__ WT,
                                              float* __restrict__ WsT,
                                              float* __restrict__ WdT) {
  int i = blockIdx.x * 256 + threadIdx.x;
  if (i < 32768) { int o = i >> 10, k = i & 1023; WT[k * 32 + o] = Win[i]; }
  if (i < 8192)  { int o2 = i >> 5, m = i & 31;   WsT[m * 256 + o2] = Ws[i]; }
  if (i < 8192)  { int c = i >> 8, o2 = i & 255;  WdT[o2 * 32 + c] = Wd[i]; }
}

// ---------------- proj_in: h0[b,o,t] = sum_k WT[k][o]*spec[b,t,k] + bias ----------------
__global__ __launch_bounds__(256) void k_proj_in(const float* __restrict__ spec,
                                                 const float* __restrict__ WT,
                                                 const float* __restrict__ bias,
                                                 float* __restrict__ h0) {
  __shared__ float specL[8][1024];
  __shared__ float red[32][8][8];   // [o][tt][p]
  int b  = blockIdx.x >> 4;
  int t0 = (blockIdx.x & 15) * 8;
  for (int i = threadIdx.x; i < 8192; i += 256) {
    int tt = i >> 10, k = i & 1023;
    specL[tt][k] = spec[(b * 128 + t0 + tt) * 1024 + k];
  }
  __syncthreads();
  int o = threadIdx.x & 31, p = threadIdx.x >> 5;
  float part[8] = {0.f,0.f,0.f,0.f,0.f,0.f,0.f,0.f};
  for (int i = 0; i < 128; ++i) {
    int k = p * 128 + ((i + p * 4) & 127);   // stagger: conflict-free banks across p
    float w = WT[k * 32 + o];
#pragma unroll
    for (int tt = 0; tt < 8; ++tt) part[tt] += w * specL[tt][k];
  }
#pragma unroll
  for (int tt = 0; tt < 8; ++tt) red[o][tt][p] = part[tt];
  __syncthreads();
  int oo = threadIdx.x >> 3, tt2 = threadIdx.x & 7;
  float s = bias[oo];
#pragma unroll
  for (int p2 = 0; p2 < 8; ++p2) s += red[oo][tt2][p2];
  h0[b * 4096 + oo * 128 + t0 + tt2] = s;
}

// ---------------- 8-block anticausal chain, one WG per batch ----------------
__global__ __launch_bounds__(1024) void k_chain(const float* __restrict__ h0,
                                                const float* __restrict__ bw,
                                                const float* __restrict__ bb,
                                                float* __restrict__ accout) {
  __shared__ float hL[32][128];
  __shared__ float w0L[32][32], w1L[32][32];
  __shared__ float bL[32];
  __shared__ float red[16];
  __shared__ float normL;
  int b = blockIdx.x;
  int tid = threadIdx.x;
  int t = tid & 127, og = tid >> 7;   // og 0..7
  for (int i = tid; i < 4096; i += 1024) hL[i >> 7][i & 127] = h0[b * 4096 + i];
  float acc[4] = {0.f, 0.f, 0.f, 0.f};
  const int DIL[8] = {1, 2, 4, 8, 16, 32, 64, 1};
  for (int blk = 0; blk < 8; ++blk) {
    __syncthreads();
    {
      int o = tid >> 5, m = tid & 31;   // tid < 1024 covers all 32x32
      w0L[o][m] = bw[((blk * 32 + o) * 32 + m) * 2 + 0];
      w1L[o][m] = bw[((blk * 32 + o) * 32 + m) * 2 + 1];
      if (tid < 32) bL[tid] = bb[blk * 32 + tid];
    }
    __syncthreads();
    int d = DIL[blk];
    int t2 = t + d;
    int t2c = (t2 < 128) ? t2 : 0;
    float fm = (t2 < 128) ? 1.f : 0.f;
    float y[4];
#pragma unroll
    for (int n = 0; n < 4; ++n) y[n] = bL[og * 4 + n];
    for (int m = 0; m < 32; ++m) {
      float hv = hL[m][t];
      float hf = hL[m][t2c] * fm;
#pragma unroll
      for (int n = 0; n < 4; ++n)
        y[n] += w0L[og * 4 + n][m] * hv + w1L[og * 4 + n][m] * hf;
    }
    float lmax = 0.f;
#pragma unroll
    for (int n = 0; n < 4; ++n) {
      float s = y[n];
      s = (s > 0.f) ? s : 0.2f * s;     // leaky_relu 0.2
      s += hL[og * 4 + n][t];           // residual
      y[n] = s;
      lmax = fmaxf(lmax, fabsf(s));
    }
    for (int off = 32; off > 0; off >>= 1)
      lmax = fmaxf(lmax, __shfl_down(lmax, off, 64));
    if ((tid & 63) == 0) red[tid >> 6] = lmax;
    __syncthreads();
    if (tid == 0) {
      float m = 0.f;
      for (int i2 = 0; i2 < 16; ++i2) m = fmaxf(m, red[i2]);
      normL = 1.f / (m + 1e-8f);
    }
    __syncthreads();
    float nm = normL;
#pragma unroll
    for (int n = 0; n < 4; ++n) {
      float hv = y[n] * nm;
      hL[og * 4 + n][t] = hv;
      acc[n] += hv;
    }
  }
#pragma unroll
  for (int n = 0; n < 4; ++n)
    accout[b * 4096 + t * 32 + og * 4 + n] = acc[n];
}

// ---------------- sparse (relu proj 32->256, to d_out) + dense (256->32, to ws) ----------------
__global__ __launch_bounds__(256) void k_sparse_dense(const float* __restrict__ acc,
                                                      const float* __restrict__ WsT,
                                                      const float* __restrict__ bs,
                                                      const float* __restrict__ WdT,
                                                      const float* __restrict__ bd,
                                                      float* __restrict__ out_sparse,
                                                      float* __restrict__ v) {
  __shared__ float accL[32];
  __shared__ float sL[256];
  __shared__ float red[8][32];
  int b = blockIdx.x >> 7, t = blockIdx.x & 127;
  int tid = threadIdx.x;
  if (tid < 32) accL[tid] = acc[b * 4096 + t * 32 + tid];
  __syncthreads();
  float s = bs[tid];
  for (int m = 0; m < 32; ++m) s += WsT[m * 256 + tid] * accL[m];
  s = fmaxf(s, 0.f);
  out_sparse[b * 32768 + tid * 128 + t] = s;
  sL[tid] = s;
  __syncthreads();
  int c = tid & 31, p = tid >> 5;
  float part = 0.f;
  for (int j = 0; j < 32; ++j) {
    int o2 = p * 32 + j;
    part += WdT[o2 * 32 + c] * sL[o2];
  }
  red[p][c] = part;
  __syncthreads();
  if (tid < 32) {
    float vv = bd[tid];
    for (int p2 = 0; p2 < 8; ++p2) vv += red[p2][tid];
    v[b * 4096 + tid * 128 + t] = vv;
  }
}

// ---------------- resonance frames: irfft_2048(c^(f+1)) * hann, f<32 only ----------------
__global__ __launch_bounds__(256) void k_res_frames(const float* __restrict__ resin,
                                                    float* __restrict__ frames) {
  __shared__ float2 buf[2048];
  int c = blockIdx.x >> 5;
  int f = blockIdx.x & 31;
  float e = (float)(f + 1);
  for (int k = threadIdx.x; k < 2048; k += 256) {
    int kk = (k <= 1024) ? k : 2048 - k;   // Hermitian (real) extension
    float cv = resin[c * 1025 + kk];
    cv = fminf(fmaxf(cv, 0.f), 0.9999f);
    float m = __powf(cv, e);
    buf[__brev((unsigned)k) >> 21] = make_float2(m, 0.f);
  }
  __syncthreads();
  fft2048_stages(buf, threadIdx.x);
  for (int j = threadIdx.x; j < 2048; j += 256) {
    float h = 0.5f - 0.5f * __cosf(0.0030679615757712823f * (float)j);
    frames[(c * 32 + f) * 2048 + j] = buf[j].x * (1.f / 2048.f) * h;
  }
}

// ---------------- overlap-add (hop 1024): at most 2 frames per sample ----------------
__global__ __launch_bounds__(256) void k_res_assemble(const float* __restrict__ frames,
                                                      float* __restrict__ res) {
  int i = blockIdx.x * 256 + threadIdx.x;   // 0 .. 32*32768
  int c = i >> 15, s = i & 32767;
  int g = s >> 10, j0 = s & 1023;
  float v = frames[(c * 32 + g) * 2048 + j0];
  if (g > 0) v += frames[(c * 32 + g - 1) * 2048 + j0 + 1024];
  res[i] = v;
}

// ---------------- final conv: y[b,256q+r] += sum_c sum_u v[b,c,q-u]*res[c,256u+r] ----------------
// Block = (b, q-tile of 16, u-chunk of 16, c-half of 16). Fully unrolled 16x16 FMA
// core with a static 31-float register window over zero-padded LDS v rows.
// q0,u0 are multiples of 16 -> window start (q0-u0+16 in padded coords) is
// 16-aligned -> 8 ds_read_b128 per (c,u-chunk). u>q terms fall in the zero pad.
#define VROW 176   // 31 zeros | 128 v | 17 zeros  (stride 176 floats = 704B, 16B-aligned)
__global__ __launch_bounds__(256) void k_conv(const float* __restrict__ v,
                                              const float* __restrict__ res,
                                              float* __restrict__ y) {
  __shared__ __align__(16) float vLp[16 * VROW];
  int idx = blockIdx.x;
  int cg = idx & 1;
  int uc = (idx >> 1) & 7;
  int qt = (idx >> 4) & 7;
  int b  = idx >> 7;
  if (uc > qt) return;            // u0 > q0 -> all contributions zero (uniform)
  int q0 = qt * 16;
  int u0 = uc * 16;
  int c0 = cg * 16;
  int r = threadIdx.x;

  // zero pads + stage v rows for this c-half
  for (int i = threadIdx.x; i < 16 * VROW; i += 256) vLp[i] = 0.f;
  __syncthreads();
  for (int i = threadIdx.x; i < 2048; i += 256) {
    int c2 = i >> 7, t = i & 127;
    vLp[c2 * VROW + 31 + t] = v[b * 4096 + (c0 + c2) * 128 + t];
  }
  __syncthreads();

  float acc[16];
#pragma unroll
  for (int qi = 0; qi < 16; ++qi) acc[qi] = 0.f;

  int wbase = q0 - u0 + 16;       // padded-coords start of the 31-float window, mult of 16
  for (int c2 = 0; c2 < 16; ++c2) {
    const float4* wrow = (const float4*)&vLp[c2 * VROW + wbase];
    float w[32];
#pragma unroll
    for (int i = 0; i < 8; ++i) {
      float4 t4 = wrow[i];
      w[4 * i + 0] = t4.x; w[4 * i + 1] = t4.y; w[4 * i + 2] = t4.z; w[4 * i + 3] = t4.w;
    }
    const float* rrow = res + (c0 + c2) * 32768 + u0 * 256 + r;
    float rv[16];
#pragma unroll
    for (int k = 0; k < 16; ++k) rv[k] = rrow[k * 256];
    // w[m] == v[c][ q0 - u0 - 15 + m ] (zero-padded); v[q0+qi-(u0+k)] = w[15-k+qi]
#pragma unroll
    for (int k = 0; k < 16; ++k)
#pragma unroll
      for (int qi = 0; qi < 16; ++qi) acc[qi] += w[15 - k + qi] * rv[k];
  }
#pragma unroll
  for (int qi = 0; qi < 16; ++qi)
    atomicAdd(&y[b * 32768 + (q0 + qi) * 256 + r], acc[qi]);
}

extern "C" void kernel_launch(void* const* d_in, const int* in_sizes, int n_in,
                              void* d_out, int out_size, void* d_ws, size_t ws_size,
                              hipStream_t stream) {
  const float* audio = (const float*)d_in[0];
  const float* Win   = (const float*)d_in[1];
  const float* bin   = (const float*)d_in[2];
  const float* bw    = (const float*)d_in[3];
  const float* bb    = (const float*)d_in[4];
  const float* Ws    = (const float*)d_in[5];
  const float* bs    = (const float*)d_in[6];
  const float* Wd    = (const float*)d_in[7];
  const float* bd    = (const float*)d_in[8];
  const float* reson = (const float*)d_in[9];

  float* out = (float*)d_out;           // [0,1048576) = y ; [1048576,2097152) = sparse
  float* ws  = (float*)d_ws;

  float* spec   = ws + WS_SPEC;
  float* h0     = ws + WS_H0;
  float* accb   = ws + WS_ACC;
  float* vbuf   = ws + WS_V;
  float* WT     = ws + WS_WTIN;
  float* WsT    = ws + WS_WST;
  float* WdT    = ws + WS_WDT;
  float* frames = ws + WS_FRAMES;
  float* resbuf = ws + WS_RES;

  // zero y region (atomicAdd target); d_out is poisoned before every launch
  hipMemsetAsync(d_out, 0, 1048576u * sizeof(float), stream);

  k_prep<<<128, 256, 0, stream>>>(Win, Ws, Wd, WT, WsT, WdT);
  k_res_frames<<<1024, 256, 0, stream>>>(reson, frames);
  k_res_assemble<<<4096, 256, 0, stream>>>(frames, resbuf);
  k_stft<<<4096, 256, 0, stream>>>(audio, spec);
  k_proj_in<<<512, 256, 0, stream>>>(spec, WT, bin, h0);
  k_chain<<<32, 1024, 0, stream>>>(h0, bw, bb, accb);
  k_sparse_dense<<<4096, 256, 0, stream>>>(accb, WsT, bs, WdT, bd, out + 1048576, vbuf);
  k_conv<<<4096, 256, 0, stream>>>(vbuf, resbuf, out);
}

// Round 3
// 294.652 us; speedup vs baseline: 1.2667x; 1.1115x over previous
//
#include <hip/hip_runtime.h>

#define PI_F 3.14159265358979323846f

// ---------------- workspace layout (float offsets) ----------------
#define WS_SPEC   0u          // 32*128*1024  [b][t][k]
#define WS_H0     4194304u    // 32*32*128    [b][o][t]
#define WS_ACC    4325376u    // 32*128*32    [b][t][o]
#define WS_V      4456448u    // 32*32*128    [b][c][t]
#define WS_WTIN   4587520u    // 1024*32      [k][o]
#define WS_WST    4620288u    // 32*256       [m][o2]
#define WS_WDT    4628480u    // 256*32       [o2][c]
#define WS_FRAMES 4636672u    // 32*32*2048   [c][f][j]
#define WS_RES    6733824u    // 32*32768     [c][s]
// total 7782400 floats = ~29.7 MB

// ---- 2048-pt complex DIT FFT, input already in bit-reversed order, 256 thr ----
__device__ __forceinline__ void fft2048_stages(float2* buf, int tid) {
  for (int stage = 0; stage < 11; ++stage) {
    int half = 1 << stage;
    float base = -PI_F / (float)half;   // -2*pi/len
    for (int t = tid; t < 1024; t += 256) {
      int j  = t & (half - 1);
      int i0 = ((t >> stage) << (stage + 1)) + j;
      int i1 = i0 + half;
      float s, c;
      __sincosf(base * (float)j, &s, &c);   // e^{-i*2pi*j/len} = c + i*s
      float2 u = buf[i0];
      float2 w = buf[i1];
      float tr = c * w.x - s * w.y;
      float ti = c * w.y + s * w.x;
      buf[i0] = make_float2(u.x + tr, u.y + ti);
      buf[i1] = make_float2(u.x - tr, u.y - ti);
    }
    __syncthreads();
  }
}

// ---------------- STFT: |rfft(frame*hann)|/sqrt(2048), keep k<1024 ----------------
__global__ __launch_bounds__(256) void k_stft(const float* __restrict__ audio,
                                              float* __restrict__ spec) {
  __shared__ float2 buf[2048];
  int b = blockIdx.x >> 7;
  int f = blockIdx.x & 127;
  for (int j = threadIdx.x; j < 2048; j += 256) {
    int idx = f * 256 + j;
    float v = (idx < 32768) ? audio[b * 32768 + idx] : 0.f;
    float h = 0.5f - 0.5f * __cosf(0.0030679615757712823f * (float)j); // 2pi/2048
    buf[__brev((unsigned)j) >> 21] = make_float2(v * h, 0.f);
  }
  __syncthreads();
  fft2048_stages(buf, threadIdx.x);
  const float scale = 0.022097086912079608f;  // 1/sqrt(2048)
  for (int k = threadIdx.x; k < 1024; k += 256) {
    float2 X = buf[k];
    spec[(b * 128 + f) * 1024 + k] = sqrtf(X.x * X.x + X.y * X.y) * scale;
  }
}

// ---------------- weight transposes ----------------
__global__ __launch_bounds__(256) void k_prep(const float* __restrict__ Win,
                                              const float* __restrict__ Ws,
                                              const float* __restrict__ Wd,
                                              float* __restrict__ WT,
                                              float* __restrict__ WsT,
                                              float* __restrict__ WdT) {
  int i = blockIdx.x * 256 + threadIdx.x;
  if (i < 32768) { int o = i >> 10, k = i & 1023; WT[k * 32 + o] = Win[i]; }
  if (i < 8192)  { int o2 = i >> 5, m = i & 31;   WsT[m * 256 + o2] = Ws[i]; }
  if (i < 8192)  { int c = i >> 8, o2 = i & 255;  WdT[o2 * 32 + c] = Wd[i]; }
}

// ---------------- proj_in: h0[b,o,t] = sum_k WT[k][o]*spec[b,t,k] + bias ----------------
__global__ __launch_bounds__(256) void k_proj_in(const float* __restrict__ spec,
                                                 const float* __restrict__ WT,
                                                 const float* __restrict__ bias,
                                                 float* __restrict__ h0) {
  __shared__ float specL[8][1024];
  __shared__ float red[32][8][8];   // [o][tt][p]
  int b  = blockIdx.x >> 4;
  int t0 = (blockIdx.x & 15) * 8;
  for (int i = threadIdx.x; i < 8192; i += 256) {
    int tt = i >> 10, k = i & 1023;
    specL[tt][k] = spec[(b * 128 + t0 + tt) * 1024 + k];
  }
  __syncthreads();
  int o = threadIdx.x & 31, p = threadIdx.x >> 5;
  float part[8] = {0.f,0.f,0.f,0.f,0.f,0.f,0.f,0.f};
  for (int i = 0; i < 128; ++i) {
    int k = p * 128 + ((i + p * 4) & 127);   // stagger: conflict-free banks across p
    float w = WT[k * 32 + o];
#pragma unroll
    for (int tt = 0; tt < 8; ++tt) part[tt] += w * specL[tt][k];
  }
#pragma unroll
  for (int tt = 0; tt < 8; ++tt) red[o][tt][p] = part[tt];
  __syncthreads();
  int oo = threadIdx.x >> 3, tt2 = threadIdx.x & 7;
  float s = bias[oo];
#pragma unroll
  for (int p2 = 0; p2 < 8; ++p2) s += red[oo][tt2][p2];
  h0[b * 4096 + oo * 128 + t0 + tt2] = s;
}

// ---------------- 8-block anticausal chain, one WG per batch ----------------
__global__ __launch_bounds__(1024) void k_chain(const float* __restrict__ h0,
                                                const float* __restrict__ bw,
                                                const float* __restrict__ bb,
                                                float* __restrict__ accout) {
  __shared__ float hL[32][128];
  __shared__ float w0L[32][32], w1L[32][32];
  __shared__ float bL[32];
  __shared__ float red[16];
  __shared__ float normL;
  int b = blockIdx.x;
  int tid = threadIdx.x;
  int t = tid & 127, og = tid >> 7;   // og 0..7
  for (int i = tid; i < 4096; i += 1024) hL[i >> 7][i & 127] = h0[b * 4096 + i];
  float acc[4] = {0.f, 0.f, 0.f, 0.f};
  const int DIL[8] = {1, 2, 4, 8, 16, 32, 64, 1};
  for (int blk = 0; blk < 8; ++blk) {
    __syncthreads();
    {
      int o = tid >> 5, m = tid & 31;   // tid < 1024 covers all 32x32
      w0L[o][m] = bw[((blk * 32 + o) * 32 + m) * 2 + 0];
      w1L[o][m] = bw[((blk * 32 + o) * 32 + m) * 2 + 1];
      if (tid < 32) bL[tid] = bb[blk * 32 + tid];
    }
    __syncthreads();
    int d = DIL[blk];
    int t2 = t + d;
    int t2c = (t2 < 128) ? t2 : 0;
    float fm = (t2 < 128) ? 1.f : 0.f;
    float y[4];
#pragma unroll
    for (int n = 0; n < 4; ++n) y[n] = bL[og * 4 + n];
    for (int m = 0; m < 32; ++m) {
      float hv = hL[m][t];
      float hf = hL[m][t2c] * fm;
#pragma unroll
      for (int n = 0; n < 4; ++n)
        y[n] += w0L[og * 4 + n][m] * hv + w1L[og * 4 + n][m] * hf;
    }
    float lmax = 0.f;
#pragma unroll
    for (int n = 0; n < 4; ++n) {
      float s = y[n];
      s = (s > 0.f) ? s : 0.2f * s;     // leaky_relu 0.2
      s += hL[og * 4 + n][t];           // residual
      y[n] = s;
      lmax = fmaxf(lmax, fabsf(s));
    }
    for (int off = 32; off > 0; off >>= 1)
      lmax = fmaxf(lmax, __shfl_down(lmax, off, 64));
    if ((tid & 63) == 0) red[tid >> 6] = lmax;
    __syncthreads();
    if (tid == 0) {
      float m = 0.f;
      for (int i2 = 0; i2 < 16; ++i2) m = fmaxf(m, red[i2]);
      normL = 1.f / (m + 1e-8f);
    }
    __syncthreads();
    float nm = normL;
#pragma unroll
    for (int n = 0; n < 4; ++n) {
      float hv = y[n] * nm;
      hL[og * 4 + n][t] = hv;
      acc[n] += hv;
    }
  }
#pragma unroll
  for (int n = 0; n < 4; ++n)
    accout[b * 4096 + t * 32 + og * 4 + n] = acc[n];
}

// ---------------- sparse (relu proj 32->256, to d_out) + dense (256->32, to ws) ----------------
__global__ __launch_bounds__(256) void k_sparse_dense(const float* __restrict__ acc,
                                                      const float* __restrict__ WsT,
                                                      const float* __restrict__ bs,
                                                      const float* __restrict__ WdT,
                                                      const float* __restrict__ bd,
                                                      float* __restrict__ out_sparse,
                                                      float* __restrict__ v) {
  __shared__ float accL[32];
  __shared__ float sL[256];
  __shared__ float red[8][32];
  int b = blockIdx.x >> 7, t = blockIdx.x & 127;
  int tid = threadIdx.x;
  if (tid < 32) accL[tid] = acc[b * 4096 + t * 32 + tid];
  __syncthreads();
  float s = bs[tid];
  for (int m = 0; m < 32; ++m) s += WsT[m * 256 + tid] * accL[m];
  s = fmaxf(s, 0.f);
  out_sparse[b * 32768 + tid * 128 + t] = s;
  sL[tid] = s;
  __syncthreads();
  int c = tid & 31, p = tid >> 5;
  float part = 0.f;
  for (int j = 0; j < 32; ++j) {
    int o2 = p * 32 + j;
    part += WdT[o2 * 32 + c] * sL[o2];
  }
  red[p][c] = part;
  __syncthreads();
  if (tid < 32) {
    float vv = bd[tid];
    for (int p2 = 0; p2 < 8; ++p2) vv += red[p2][tid];
    v[b * 4096 + tid * 128 + t] = vv;
  }
}

// ---------------- resonance frames: irfft_2048(c^(f+1)) * hann, f<32 only ----------------
__global__ __launch_bounds__(256) void k_res_frames(const float* __restrict__ resin,
                                                    float* __restrict__ frames) {
  __shared__ float2 buf[2048];
  int c = blockIdx.x >> 5;
  int f = blockIdx.x & 31;
  float e = (float)(f + 1);
  for (int k = threadIdx.x; k < 2048; k += 256) {
    int kk = (k <= 1024) ? k : 2048 - k;   // Hermitian (real) extension
    float cv = resin[c * 1025 + kk];
    cv = fminf(fmaxf(cv, 0.f), 0.9999f);
    float m = __powf(cv, e);
    buf[__brev((unsigned)k) >> 21] = make_float2(m, 0.f);
  }
  __syncthreads();
  fft2048_stages(buf, threadIdx.x);
  for (int j = threadIdx.x; j < 2048; j += 256) {
    float h = 0.5f - 0.5f * __cosf(0.0030679615757712823f * (float)j);
    frames[(c * 32 + f) * 2048 + j] = buf[j].x * (1.f / 2048.f) * h;
  }
}

// ---------------- overlap-add (hop 1024): at most 2 frames per sample ----------------
__global__ __launch_bounds__(256) void k_res_assemble(const float* __restrict__ frames,
                                                      float* __restrict__ res) {
  int i = blockIdx.x * 256 + threadIdx.x;   // 0 .. 32*32768
  int c = i >> 15, s = i & 32767;
  int g = s >> 10, j0 = s & 1023;
  float v = frames[(c * 32 + g) * 2048 + j0];
  if (g > 0) v += frames[(c * 32 + g - 1) * 2048 + j0 + 1024];
  res[i] = v;
}

// ---------------- final conv: y[b,256q+r] += sum_c sum_u v[b,c,q-u]*res[c,256u+r] ----------------
// Block = (b, one of 36 valid (qt,uc) pairs), ALL 32 channels per block.
// Static 31-float register window over zero-padded LDS v rows (wbase 16-aligned
// -> 8 ds_read_b128, wave-uniform -> broadcast, no conflicts). rv (res) loads are
// ping-pong double-buffered across the c loop so each 16-load group has a full
// 256-FMA block (~512 cyc) in flight before first use -> hides L2 latency.
#define VROW 176   // 31 zeros | 128 v | 17 zeros  (stride 176 floats, 16B-aligned)
__global__ __launch_bounds__(256) void k_conv(const float* __restrict__ v,
                                              const float* __restrict__ res,
                                              float* __restrict__ y) {
  __shared__ __align__(16) float vLp[32 * VROW];
  int idx = blockIdx.x;
  int b = idx / 36;
  int p = idx - b * 36;
  // decode triangular pair index p -> (qt, uc), uc <= qt
  int qt = (int)((sqrtf(8.f * (float)p + 1.f) - 1.f) * 0.5f + 1e-4f);
  int uc = p - ((qt * (qt + 1)) >> 1);
  int q0 = qt * 16;
  int u0 = uc * 16;
  int r = threadIdx.x;

  // zero pads + stage all 32 v rows
  for (int i = threadIdx.x; i < 32 * VROW; i += 256) vLp[i] = 0.f;
  __syncthreads();
  for (int i = threadIdx.x; i < 4096; i += 256) {
    int c2 = i >> 7, t = i & 127;
    vLp[c2 * VROW + 31 + t] = v[b * 4096 + i];
  }
  __syncthreads();

  float acc[16];
#pragma unroll
  for (int qi = 0; qi < 16; ++qi) acc[qi] = 0.f;

  int wbase = q0 - u0 + 16;       // padded-coords window start, multiple of 16
  const float* rbase = res + u0 * 256 + r;   // row c: rbase + c*32768

  float rvA[16], rvB[16];
#pragma unroll
  for (int k = 0; k < 16; ++k) rvA[k] = rbase[k * 256];

  for (int c2 = 0; c2 < 32; c2 += 2) {
    // prefetch row c2+1 into B
    const float* rn1 = rbase + (c2 + 1) * 32768;
#pragma unroll
    for (int k = 0; k < 16; ++k) rvB[k] = rn1[k * 256];
    {
      const float4* wrow = (const float4*)&vLp[c2 * VROW + wbase];
      float w[32];
#pragma unroll
      for (int i = 0; i < 8; ++i) {
        float4 t4 = wrow[i];
        w[4 * i + 0] = t4.x; w[4 * i + 1] = t4.y; w[4 * i + 2] = t4.z; w[4 * i + 3] = t4.w;
      }
      // w[m] == v[c2][q0-u0-15+m] (zero-padded); v[q0+qi-(u0+k)] = w[15-k+qi]
#pragma unroll
      for (int k = 0; k < 16; ++k)
#pragma unroll
        for (int qi = 0; qi < 16; ++qi) acc[qi] += w[15 - k + qi] * rvA[k];
    }
    // prefetch row c2+2 into A (clamped redundant load on last iter)
    int cn = (c2 + 2 < 32) ? (c2 + 2) : 31;
    const float* rn2 = rbase + cn * 32768;
#pragma unroll
    for (int k = 0; k < 16; ++k) rvA[k] = rn2[k * 256];
    {
      const float4* wrow = (const float4*)&vLp[(c2 + 1) * VROW + wbase];
      float w[32];
#pragma unroll
      for (int i = 0; i < 8; ++i) {
        float4 t4 = wrow[i];
        w[4 * i + 0] = t4.x; w[4 * i + 1] = t4.y; w[4 * i + 2] = t4.z; w[4 * i + 3] = t4.w;
      }
#pragma unroll
      for (int k = 0; k < 16; ++k)
#pragma unroll
        for (int qi = 0; qi < 16; ++qi) acc[qi] += w[15 - k + qi] * rvB[k];
    }
  }
#pragma unroll
  for (int qi = 0; qi < 16; ++qi)
    atomicAdd(&y[b * 32768 + (q0 + qi) * 256 + r], acc[qi]);
}

extern "C" void kernel_launch(void* const* d_in, const int* in_sizes, int n_in,
                              void* d_out, int out_size, void* d_ws, size_t ws_size,
                              hipStream_t stream) {
  const float* audio = (const float*)d_in[0];
  const float* Win   = (const float*)d_in[1];
  const float* bin   = (const float*)d_in[2];
  const float* bw    = (const float*)d_in[3];
  const float* bb    = (const float*)d_in[4];
  const float* Ws    = (const float*)d_in[5];
  const float* bs    = (const float*)d_in[6];
  const float* Wd    = (const float*)d_in[7];
  const float* bd    = (const float*)d_in[8];
  const float* reson = (const float*)d_in[9];

  float* out = (float*)d_out;           // [0,1048576) = y ; [1048576,2097152) = sparse
  float* ws  = (float*)d_ws;

  float* spec   = ws + WS_SPEC;
  float* h0     = ws + WS_H0;
  float* accb   = ws + WS_ACC;
  float* vbuf   = ws + WS_V;
  float* WT     = ws + WS_WTIN;
  float* WsT    = ws + WS_WST;
  float* WdT    = ws + WS_WDT;
  float* frames = ws + WS_FRAMES;
  float* resbuf = ws + WS_RES;

  // zero y region (atomicAdd target); d_out is poisoned before every launch
  hipMemsetAsync(d_out, 0, 1048576u * sizeof(float), stream);

  k_prep<<<128, 256, 0, stream>>>(Win, Ws, Wd, WT, WsT, WdT);
  k_res_frames<<<1024, 256, 0, stream>>>(reson, frames);
  k_res_assemble<<<4096, 256, 0, stream>>>(frames, resbuf);
  k_stft<<<4096, 256, 0, stream>>>(audio, spec);
  k_proj_in<<<512, 256, 0, stream>>>(spec, WT, bin, h0);
  k_chain<<<32, 1024, 0, stream>>>(h0, bw, bb, accb);
  k_sparse_dense<<<4096, 256, 0, stream>>>(accb, WsT, bs, WdT, bd, out + 1048576, vbuf);
  k_conv<<<1152, 256, 0, stream>>>(vbuf, resbuf, out);
}